// Round 9
// baseline (507.522 us; speedup 1.0000x reference)
//
#include <hip/hip_runtime.h>
#include <math.h>

typedef unsigned short u16;
typedef __attribute__((ext_vector_type(4))) unsigned short us4;
typedef __attribute__((ext_vector_type(8))) unsigned short us8;
typedef __attribute__((ext_vector_type(4))) float f4;
typedef __attribute__((ext_vector_type(8))) short bf16x8;
typedef __attribute__((ext_vector_type(4))) float f32x4;

#define S_LEN   4096
#define D_MODEL 1024
#define N_HEAD  16
#define D_HEAD  64
#define FF_DIM  2048
#define TOKENS  16384  // B*S

__device__ __forceinline__ float bf2f(u16 u) {
  union { float f; unsigned u; } x; x.u = ((unsigned)u) << 16; return x.f;
}
__device__ __forceinline__ u16 f2bf(float f) {
  union { float f; unsigned u; } x; x.f = f;
  return (u16)((x.u + 0x7FFFu + ((x.u >> 16) & 1u)) >> 16);
}

__device__ __forceinline__ void gll16(const void* g, void* l) {
  __builtin_amdgcn_global_load_lds(
      (const __attribute__((address_space(1))) void*)g,
      (__attribute__((address_space(3))) void*)l, 16, 0, 0);
}

// barrier + compiler-only memory fence (no extra runtime waits)
#define BARF() do { __builtin_amdgcn_s_barrier(); asm volatile("" ::: "memory"); } while (0)

// ---------------------------------------------------------------------------
// Fused f32 -> bf16 weight conversion for all 6 weight matrices.
// ---------------------------------------------------------------------------
__global__ void __launch_bounds__(256)
cvt6_k(const float* __restrict__ qw, const float* __restrict__ kw,
       const float* __restrict__ vw, const float* __restrict__ ow,
       const float* __restrict__ f1w, const float* __restrict__ f2w,
       u16* __restrict__ wq, u16* __restrict__ wk, u16* __restrict__ wv,
       u16* __restrict__ wo, u16* __restrict__ w1, u16* __restrict__ w2)
{
  const int id = blockIdx.x;
  const float* src; u16* dst; int base;
  if      (id < 1024) { src = qw;  dst = wq; base = 0; }
  else if (id < 2048) { src = kw;  dst = wk; base = 1024; }
  else if (id < 3072) { src = vw;  dst = wv; base = 2048; }
  else if (id < 4096) { src = ow;  dst = wo; base = 3072; }
  else if (id < 6144) { src = f1w; dst = w1; base = 4096; }
  else                { src = f2w; dst = w2; base = 6144; }
  const size_t i = ((size_t)(id - base) * 256 + threadIdx.x) * 4;
  const f4 v = *(const f4*)(src + i);
  us4 o;
  o[0] = f2bf(v[0]); o[1] = f2bf(v[1]); o[2] = f2bf(v[2]); o[3] = f2bf(v[3]);
  *(us4*)(dst + i) = o;
}

// ---------------------------------------------------------------------------
// RMSNorm: one block per row of 1024. f32 in -> bf16 out.
// ---------------------------------------------------------------------------
__global__ void __launch_bounds__(256)
rmsnorm_k(const float* __restrict__ in, const float* __restrict__ scale,
          u16* __restrict__ out)
{
  const int row = blockIdx.x;
  const int tid = threadIdx.x;
  const f4 v = *(const f4*)(in + (size_t)row * D_MODEL + tid * 4);
  float ss = v[0]*v[0] + v[1]*v[1] + v[2]*v[2] + v[3]*v[3];
#pragma unroll
  for (int off = 32; off > 0; off >>= 1) ss += __shfl_down(ss, off, 64);
  __shared__ float red[4];
  const int wid = tid >> 6, lane = tid & 63;
  if (lane == 0) red[wid] = ss;
  __syncthreads();
  const float tot = red[0] + red[1] + red[2] + red[3];
  const float r = rsqrtf(tot * (1.0f / 1024.0f) + 1e-6f);
  const f4 sc = *(const f4*)(scale + tid * 4);
  us4 o;
  o[0] = f2bf(v[0] * r * sc[0]);
  o[1] = f2bf(v[1] * r * sc[1]);
  o[2] = f2bf(v[2] * r * sc[2]);
  o[3] = f2bf(v[3] * r * sc[3]);
  *(us4*)(out + (size_t)row * D_MODEL + tid * 4) = o;
}

// ---------------------------------------------------------------------------
// 256x256 GEMM, 2 fat phases per K-tile (BK=64), 8 waves (2M x 4N),
// double-buffered 128 KiB LDS. FRAGMENT-MAJOR LDS layout:
//   region + bf*16384 + f*512 + lane*8 (u16), f = rg*2 + kk,
//   rg = rowgroup (16 rows), kk = K-half (32 k). Each ds_read_b128 is
//   base + lane*16B -> canonical linear pattern, ZERO bank conflicts.
// The (row,k)->(frag,lane) shuffle happens in the per-lane GLOBAL source
// address of global_load_lds (LDS dest stays linear; m173 pattern).
// Schedule/vmcnt ledger identical to the verified round-7 kernel:
//  phase0: LDB all (8 reads, B in regs for tile); STAGE B(t+1) (4 gll16);
//          4x CHUNK{2 reads A-h0; 8 MFMA}; vmcnt(4); barrier.
//  phase1: STAGE A(t+1) (4 gll16); 4x CHUNK{A-h1}; vmcnt(2); barrier.
// EPI 0: QKV (W = concat [3072][1024]); z = blockIdx.y>>2:
//        z<2 -> transpose scatter to [bh][d][s]; z=2 -> v2 [bh][s][d].
// EPI 2: f32 out = acc + bias + res.   EPI 3: bf16 swiglu out.
// ---------------------------------------------------------------------------
template<int EPI>
__global__ __launch_bounds__(512, 2)
void g8k(const u16* __restrict__ Ag, const u16* __restrict__ Wg,
         const float* __restrict__ bq, const float* __restrict__ bk,
         const float* __restrict__ bv, const float* __restrict__ res,
         void* __restrict__ C0, void* __restrict__ C1, void* __restrict__ C2,
         int N, int K)
{
  __shared__ __align__(16) u16 lds[65536];   // A: [0,32768) B: [32768,65536)
  const int tid = threadIdx.x;
  const int w = tid >> 6, l = tid & 63;
  const int fr = l & 15, fq = l >> 4;
  const int wm = w >> 2, wn = w & 3;
  const int m0 = blockIdx.x << 8, n0 = blockIdx.y << 8;
  const int NT = K >> 6;

  // stage half hf (rowgroups hf*8..+8, both kk) of tile nt into buffer bfs
  auto STAGE = [&](int isA, int hf, int bfs, int nt) {
    const u16* G = isA ? Ag : Wg;
    const int rbase = (isA ? m0 : n0);
    const int kb = (nt < NT ? nt << 6 : 0);
    u16* region = lds + (isA ? 0 : 32768) + bfs * 16384;
#pragma unroll
    for (int j = 0; j < 2; ++j) {
      const int f = hf * 16 + j * 8 + w;           // wave-uniform
      const int rg = f >> 1, kk = f & 1;
      const int row = rbase + rg * 16 + fr;        // per-lane
      const int col = kb + kk * 32 + fq * 8;       // per-lane
      gll16(G + (size_t)row * K + col, region + f * 512);
    }
  };

  f32x4 acc[8][4] = {};
  bf16x8 b_frag[4][2];

  auto LDB_ALL = [&](int bf) {
#pragma unroll
    for (int ni = 0; ni < 4; ++ni)
#pragma unroll
      for (int kk = 0; kk < 2; ++kk) {
        const int rg = (ni >> 1) * 8 + (ni & 1) * 4 + wn;
        b_frag[ni][kk] = *(const bf16x8*)(lds + 32768 + bf * 16384
                                          + rg * 1024 + kk * 512 + l * 8);
      }
  };

  // one A-fragment chunk: 2 linear ds_read_b128 + 8 MFMA
  auto CHUNK = [&](int bf, int mh, int mi) {
    const int rg = mh * 8 + mi * 2 + wm;
    const u16* base = lds + bf * 16384 + rg * 1024 + l * 8;
    const bf16x8 a0 = *(const bf16x8*)(base);
    const bf16x8 a1 = *(const bf16x8*)(base + 512);
    __builtin_amdgcn_s_setprio(1);
#pragma unroll
    for (int ni = 0; ni < 4; ++ni) {
      acc[mh * 4 + mi][ni] =
          __builtin_amdgcn_mfma_f32_16x16x32_bf16(a0, b_frag[ni][0], acc[mh * 4 + mi][ni], 0, 0, 0);
      acc[mh * 4 + mi][ni] =
          __builtin_amdgcn_mfma_f32_16x16x32_bf16(a1, b_frag[ni][1], acc[mh * 4 + mi][ni], 0, 0, 0);
    }
    __builtin_amdgcn_s_setprio(0);
  };

  // prologue: B(t0) then A(t0), then A(t1); keep A(t1) h1 in flight
  STAGE(0, 0, 0, 0);  // B h0 t0
  STAGE(0, 1, 0, 0);  // B h1 t0
  STAGE(1, 0, 0, 0);  // A h0 t0
  STAGE(1, 1, 0, 0);  // A h1 t0
  STAGE(1, 0, 1, 1);  // A h0 t1
  STAGE(1, 1, 1, 1);  // A h1 t1
  asm volatile("s_waitcnt vmcnt(2)" ::: "memory");
  BARF();

#pragma unroll 2
  for (int t = 0; t < NT; ++t) {
    const int bf = t & 1;
    // ---- phase 0 (A-half 0)
    LDB_ALL(bf);
    STAGE(0, 0, bf ^ 1, t + 1);   // B h0 of t+1
    STAGE(0, 1, bf ^ 1, t + 1);   // B h1 of t+1
    CHUNK(bf, 0, 0); CHUNK(bf, 0, 1); CHUNK(bf, 0, 2); CHUNK(bf, 0, 3);
    asm volatile("s_waitcnt vmcnt(4)" ::: "memory");  // drain A(t) h1
    BARF();
    // ---- phase 1 (A-half 1)
    STAGE(1, 0, bf ^ 1, t + 1);   // A h0 of t+1
    STAGE(1, 1, bf ^ 1, t + 1);   // A h1 of t+1
    CHUNK(bf, 1, 0); CHUNK(bf, 1, 1); CHUNK(bf, 1, 2); CHUNK(bf, 1, 3);
    asm volatile("s_waitcnt vmcnt(2)" ::: "memory");  // drain B(t+1)+A(t+1)h0
    BARF();
  }
  asm volatile("s_waitcnt vmcnt(0)" ::: "memory");
  __builtin_amdgcn_s_barrier();
  asm volatile("" ::: "memory");

  if constexpr (EPI == 2) {
    float* C = (float*)C0;
#pragma unroll
    for (int mi = 0; mi < 8; ++mi)
#pragma unroll
      for (int ni = 0; ni < 4; ++ni) {
        const int c = n0 + ni * 64 + wn * 16 + fr;
        const int r0 = m0 + mi * 32 + wm * 16 + fq * 4;
        const float bb = bq[c];
#pragma unroll
        for (int j = 0; j < 4; ++j)
          C[(size_t)(r0 + j) * N + c] = acc[mi][ni][j] + bb + res[(size_t)(r0 + j) * N + c];
      }
  } else if constexpr (EPI == 3) {
    u16* C = (u16*)C0;
#pragma unroll
    for (int mi = 0; mi < 8; ++mi)
#pragma unroll
      for (int ni = 0; ni < 4; ++ni) {
        const int c = n0 + ni * 64 + wn * 16 + fr;
        const int r0 = m0 + mi * 32 + wm * 16 + fq * 4;
        const float bb = bq[c];
#pragma unroll
        for (int j = 0; j < 4; ++j) {
          const float v = acc[mi][ni][j] + bb;
          const float sig = 1.0f / (1.0f + expf(-v));
          C[(size_t)(r0 + j) * N + c] = f2bf(v * sig + v);
        }
      }
  } else {
    // QKV epilogue: pack bias-added bf16 tile transposed into LDS (swizzled)
    const int z = blockIdx.y >> 2;
    const float* bias = z == 0 ? bq : (z == 1 ? bk : bv);
    const int n0l = n0 & 1023;
    const int bb = m0 >> 12, s0l = m0 & (S_LEN - 1);
#pragma unroll
    for (int mi = 0; mi < 8; ++mi)
#pragma unroll
      for (int ni = 0; ni < 4; ++ni) {
        const int c = ni * 64 + wn * 16 + fr;
        const int r0 = mi * 32 + wm * 16 + fq * 4;
        const float bv_ = bias[n0l + c];
        us4 pk;
#pragma unroll
        for (int j = 0; j < 4; ++j) pk[j] = f2bf(acc[mi][ni][j] + bv_);
        const int byte = ((c << 9) + (r0 << 1)) ^ ((c & 7) << 4);
        *(us4*)((char*)lds + byte) = pk;
      }
    __syncthreads();
    if (z < 2) {
      u16* Cout = z == 0 ? (u16*)C0 : (u16*)C1;
      const int c = tid & 255, half = tid >> 8;
      const int o = n0l + c, d = o >> 4, h = o & 15;
      const int xr = (c & 7) << 4;
      u16* dst = Cout + ((size_t)((bb << 10) + (h << 6) + d)) * S_LEN + s0l + half * 128;
#pragma unroll
      for (int u = 0; u < 16; ++u) {
        const int byte = ((c << 9) + (half << 8) + (u << 4)) ^ xr;
        const us8 v = *(const us8*)((char*)lds + byte);
        *(us8*)(dst + u * 8) = v;
      }
    } else {
      u16* Cv = (u16*)C2;
      const int d0 = n0l >> 4;
#pragma unroll
      for (int q2 = 0; q2 < 8; ++q2) {
        const int idx = q2 * 512 + tid;
        const int h = idx >> 8, r = idx & 255;
        const int xr = (h & 7) << 4;
        us8 lo, hi;
#pragma unroll
        for (int dl = 0; dl < 8; ++dl) {
          lo[dl] = *(const u16*)((char*)lds + ((((h + dl * 16) << 9) + (r << 1)) ^ xr));
          hi[dl] = *(const u16*)((char*)lds + ((((h + (dl + 8) * 16) << 9) + (r << 1)) ^ xr));
        }
        u16* dst = Cv + ((size_t)(bb * 16 + h) * S_LEN + s0l + r) * 64 + d0;
        *(us8*)dst = lo;
        *(us8*)(dst + 8) = hi;
      }
    }
  }
}

// ---------------------------------------------------------------------------
// Fused scores + softmax per (b,h). One block per bh, 4 waves.
// ---------------------------------------------------------------------------
__global__ void __launch_bounds__(256)
att_sm_k(const u16* __restrict__ qt, const u16* __restrict__ kt,
         u16* __restrict__ P)
{
  __shared__ float red[4][64][64];   // [wave][e][d]
  const int bh = blockIdx.x;
  const int tid = threadIdx.x, w = tid >> 6, l = tid & 63;
  const int fr = l & 15, fq = l >> 4;
  const u16* Qb = qt + (size_t)bh * D_HEAD * S_LEN;
  const u16* Kb = kt + (size_t)bh * D_HEAD * S_LEN;
  f32x4 acc[4][4] = {};
  const int sb = w * 1024 + fq * 8;
  for (int ks = 0; ks < 32; ++ks) {
    const int s0 = sb + ks * 32;
    bf16x8 a[4], b[4];
#pragma unroll
    for (int m = 0; m < 4; ++m)
      a[m] = *(const bf16x8*)(Qb + (size_t)(m*16 + fr) * S_LEN + s0);
#pragma unroll
    for (int n = 0; n < 4; ++n)
      b[n] = *(const bf16x8*)(Kb + (size_t)(n*16 + fr) * S_LEN + s0);
#pragma unroll
    for (int m = 0; m < 4; ++m)
#pragma unroll
      for (int n = 0; n < 4; ++n)
        acc[m][n] = __builtin_amdgcn_mfma_f32_16x16x32_bf16(a[m], b[n], acc[m][n], 0, 0, 0);
  }
#pragma unroll
  for (int m = 0; m < 4; ++m)
#pragma unroll
    for (int n = 0; n < 4; ++n)
      *(f32x4*)&red[w][n*16 + fr][m*16 + fq*4] = acc[m][n];
  __syncthreads();

  const int d = tid >> 2, sub = tid & 3;
  float p[16];
  float mx = -1e30f;
#pragma unroll
  for (int i = 0; i < 16; ++i) {
    const int e = sub * 16 + i;
    float v = red[0][e][d] + red[1][e][d] + red[2][e][d] + red[3][e][d];
    v *= 0.125f;
    p[i] = v; mx = fmaxf(mx, v);
  }
  mx = fmaxf(mx, __shfl_xor(mx, 1, 64));
  mx = fmaxf(mx, __shfl_xor(mx, 2, 64));
  float sm = 0.0f;
#pragma unroll
  for (int i = 0; i < 16; ++i) { p[i] = expf(p[i] - mx); sm += p[i]; }
  sm += __shfl_xor(sm, 1, 64);
  sm += __shfl_xor(sm, 2, 64);
  const float inv = 1.0f / sm;
  us8 o0, o1;
#pragma unroll
  for (int i = 0; i < 8; ++i) { o0[i] = f2bf(p[i] * inv); o1[i] = f2bf(p[i+8] * inv); }
  u16* dst = P + (size_t)bh * 4096 + d * 64 + sub * 16;
  *(us8*)dst = o0;
  *(us8*)(dst + 8) = o1;
}

// ---------------------------------------------------------------------------
// PV via MFMA. out[d][s] = sum_e P[d][e] * V[e][s], V given as v2[s][e].
// ---------------------------------------------------------------------------
__global__ void __launch_bounds__(256)
pv2_k(const u16* __restrict__ P, const u16* __restrict__ v2,
      u16* __restrict__ ar)
{
  const int bh = blockIdx.x, sc = blockIdx.y;
  const int b = bh >> 4, h = bh & 15;
  const int tid = threadIdx.x, w = tid >> 6, l = tid & 63;
  const int fr = l & 15, fq = l >> 4;
  const u16* Pb = P + (size_t)bh * 4096;
  const u16* Vb = v2 + (size_t)bh * D_HEAD * S_LEN;

  bf16x8 a[4][2];
#pragma unroll
  for (int m = 0; m < 4; ++m)
#pragma unroll
    for (int ks = 0; ks < 2; ++ks)
      a[m][ks] = *(const bf16x8*)(Pb + (m*16 + fr) * 64 + ks*32 + fq*8);

  const int sw = sc * 512 + w * 128;
  f32x4 acc[8][4] = {};   // [n][m]
#pragma unroll
  for (int n = 0; n < 8; ++n) {
    const u16* vp = Vb + (size_t)(sw + n*16 + fr) * 64 + fq*8;
    const bf16x8 b0 = *(const bf16x8*)(vp);
    const bf16x8 b1 = *(const bf16x8*)(vp + 32);
#pragma unroll
    for (int m = 0; m < 4; ++m)
      acc[n][m] = __builtin_amdgcn_mfma_f32_16x16x32_bf16(a[m][0], b0, acc[n][m], 0, 0, 0);
#pragma unroll
    for (int m = 0; m < 4; ++m)
      acc[n][m] = __builtin_amdgcn_mfma_f32_16x16x32_bf16(a[m][1], b1, acc[n][m], 0, 0, 0);
  }

  const int shi = sc >> 1;
  const int col0 = (sc & 1) * 512 + w * 128;
#pragma unroll
  for (int m = 0; m < 4; ++m)
#pragma unroll
    for (int j = 0; j < 4; ++j) {
      const int d = m*16 + fq*4 + j;
      const size_t base = ((size_t)b * 4096 + (d << 6) + (h << 2) + shi) * 1024 + col0;
#pragma unroll
      for (int n = 0; n < 8; ++n)
        ar[base + n*16 + fr] = f2bf(acc[n][m][j]);
    }
}

// ---------------------------------------------------------------------------
extern "C" void kernel_launch(void* const* d_in, const int* in_sizes, int n_in,
                              void* d_out, int out_size, void* d_ws, size_t ws_size,
                              hipStream_t stream)
{
  const float* x     = (const float*)d_in[0];
  const float* scale = (const float*)d_in[1];
  const float* qw = (const float*)d_in[2];
  const float* qb = (const float*)d_in[3];
  const float* kw = (const float*)d_in[4];
  const float* kb = (const float*)d_in[5];
  const float* vw = (const float*)d_in[6];
  const float* vb = (const float*)d_in[7];
  const float* ow = (const float*)d_in[8];
  const float* ob = (const float*)d_in[9];
  const float* f1w = (const float*)d_in[10];
  const float* f1b = (const float*)d_in[11];
  const float* f2w = (const float*)d_in[12];
  const float* f2b = (const float*)d_in[13];
  float* out = (float*)d_out;

  const size_t TOKD = (size_t)TOKENS * D_MODEL;
  const size_t WSZ1 = (size_t)D_MODEL * D_MODEL;
  const size_t WSZ2 = (size_t)FF_DIM * D_MODEL;
  u16* xn = (u16*)d_ws;
  u16* qt = xn + TOKD;
  u16* kt = qt + TOKD;
  u16* v2 = kt + TOKD;
  u16* wq = v2 + TOKD;        // wq,wk,wv contiguous = concat [3072][1024]
  u16* wk = wq + WSZ1;
  u16* wv = wk + WSZ1;
  u16* wo = wv + WSZ1;
  u16* w1 = wo + WSZ1;
  u16* w2 = w1 + WSZ2;
  u16* Patt = w2 + WSZ2;
  u16* hbuf = kt;             // overlays kt+v2 (dead after attention)
  u16* ar = qt;               // overlays qt (dead after att_sm)

  dim3 blk(256);
  dim3 blk8(512);

  // 0. weights f32 -> bf16
  cvt6_k<<<8192, blk, 0, stream>>>(qw, kw, vw, ow, f1w, f2w, wq, wk, wv, wo, w1, w2);
  // 1. rmsnorm(x) -> xn
  rmsnorm_k<<<TOKENS, blk, 0, stream>>>(x, scale, xn);
  // 2. QKV (merged N=3072): qt/kt [bh][d][s], v2 [bh][s][d]
  g8k<0><<<dim3(TOKENS / 256, 12), blk8, 0, stream>>>(
      xn, wq, qb, kb, vb, nullptr, qt, kt, v2, 3072, D_MODEL);
  // 3. scores + softmax -> Patt
  att_sm_k<<<64, blk, 0, stream>>>(qt, kt, Patt);
  // 4. PV -> ar
  pv2_k<<<dim3(64, 8), blk, 0, stream>>>(Patt, v2, ar);
  // 5. O projection + bias + residual(x) -> out (f32)
  g8k<2><<<dim3(TOKENS / 256, D_MODEL / 256), blk8, 0, stream>>>(
      ar, wo, ob, nullptr, nullptr, x, out, nullptr, nullptr, D_MODEL, D_MODEL);
  // 6. rmsnorm(out) -> xn
  rmsnorm_k<<<TOKENS, blk, 0, stream>>>(out, scale, xn);
  // 7. FFN up + swiglu -> hbuf
  g8k<3><<<dim3(TOKENS / 256, FF_DIM / 256), blk8, 0, stream>>>(
      xn, w1, f1b, nullptr, nullptr, nullptr, hbuf, nullptr, nullptr, FF_DIM, D_MODEL);
  // 8. FFN down + bias + residual(out) -> out
  g8k<2><<<dim3(TOKENS / 256, D_MODEL / 256), blk8, 0, stream>>>(
      hbuf, w2, f2b, nullptr, nullptr, out, out, nullptr, nullptr, D_MODEL, FF_DIM);
}

// Round 10
// 454.442 us; speedup vs baseline: 1.1168x; 1.1168x over previous
//
#include <hip/hip_runtime.h>
#include <math.h>

typedef unsigned short u16;
typedef __attribute__((ext_vector_type(4))) unsigned short us4;
typedef __attribute__((ext_vector_type(8))) unsigned short us8;
typedef __attribute__((ext_vector_type(4))) float f4;
typedef __attribute__((ext_vector_type(8))) short bf16x8;
typedef __attribute__((ext_vector_type(4))) float f32x4;

#define S_LEN   4096
#define D_MODEL 1024
#define N_HEAD  16
#define D_HEAD  64
#define FF_DIM  2048
#define TOKENS  16384  // B*S

__device__ __forceinline__ float bf2f(u16 u) {
  union { float f; unsigned u; } x; x.u = ((unsigned)u) << 16; return x.f;
}
__device__ __forceinline__ u16 f2bf(float f) {
  union { float f; unsigned u; } x; x.f = f;
  return (u16)((x.u + 0x7FFFu + ((x.u >> 16) & 1u)) >> 16);
}

__device__ __forceinline__ void gll16(const void* g, void* l) {
  __builtin_amdgcn_global_load_lds(
      (const __attribute__((address_space(1))) void*)g,
      (__attribute__((address_space(3))) void*)l, 16, 0, 0);
}

// ---------------------------------------------------------------------------
// Fused f32 -> bf16 weight conversion for all 6 weight matrices.
// ---------------------------------------------------------------------------
__global__ void __launch_bounds__(256)
cvt6_k(const float* __restrict__ qw, const float* __restrict__ kw,
       const float* __restrict__ vw, const float* __restrict__ ow,
       const float* __restrict__ f1w, const float* __restrict__ f2w,
       u16* __restrict__ wq, u16* __restrict__ wk, u16* __restrict__ wv,
       u16* __restrict__ wo, u16* __restrict__ w1, u16* __restrict__ w2)
{
  const int id = blockIdx.x;
  const float* src; u16* dst; int base;
  if      (id < 1024) { src = qw;  dst = wq; base = 0; }
  else if (id < 2048) { src = kw;  dst = wk; base = 1024; }
  else if (id < 3072) { src = vw;  dst = wv; base = 2048; }
  else if (id < 4096) { src = ow;  dst = wo; base = 3072; }
  else if (id < 6144) { src = f1w; dst = w1; base = 4096; }
  else                { src = f2w; dst = w2; base = 6144; }
  const size_t i = ((size_t)(id - base) * 256 + threadIdx.x) * 4;
  const f4 v = *(const f4*)(src + i);
  us4 o;
  o[0] = f2bf(v[0]); o[1] = f2bf(v[1]); o[2] = f2bf(v[2]); o[3] = f2bf(v[3]);
  *(us4*)(dst + i) = o;
}

// ---------------------------------------------------------------------------
// RMSNorm: one block per row of 1024. f32 in -> bf16 out.
// ---------------------------------------------------------------------------
__global__ void __launch_bounds__(256)
rmsnorm_k(const float* __restrict__ in, const float* __restrict__ scale,
          u16* __restrict__ out)
{
  const int row = blockIdx.x;
  const int tid = threadIdx.x;
  const f4 v = *(const f4*)(in + (size_t)row * D_MODEL + tid * 4);
  float ss = v[0]*v[0] + v[1]*v[1] + v[2]*v[2] + v[3]*v[3];
#pragma unroll
  for (int off = 32; off > 0; off >>= 1) ss += __shfl_down(ss, off, 64);
  __shared__ float red[4];
  const int wid = tid >> 6, lane = tid & 63;
  if (lane == 0) red[wid] = ss;
  __syncthreads();
  const float tot = red[0] + red[1] + red[2] + red[3];
  const float r = rsqrtf(tot * (1.0f / 1024.0f) + 1e-6f);
  const f4 sc = *(const f4*)(scale + tid * 4);
  us4 o;
  o[0] = f2bf(v[0] * r * sc[0]);
  o[1] = f2bf(v[1] * r * sc[1]);
  o[2] = f2bf(v[2] * r * sc[2]);
  o[3] = f2bf(v[3] * r * sc[3]);
  *(us4*)(out + (size_t)row * D_MODEL + tid * 4) = o;
}

// ---------------------------------------------------------------------------
// 128x256 GEMM, BK=64, SINGLE-buffered 48 KiB staging LDS (64 KiB block total
// incl. epilogue overlay) -> 2 blocks/CU, 4 waves/SIMD: block-level TLP fills
// each block's barrier/staging stall windows with the other block's MFMA.
// 8 waves as 2M x 4N, wave tile 64x64 (acc[4][4] = 64 VGPR, cap 128).
// m97-style loop per K-tile: sync; 6x gll16 (A 16KB + B 32KB, inverse-XOR
// source cols); sync (compiler emits vmcnt(0) drain); 16 ds_read_b128
// (XOR-swizzled, bijective per 8-lane group); 32 MFMA (setprio).
// LDS content rule: LDS[row][x] = G[row][x ^ (row&7)] (16B chunks x=0..7).
// EPI 0: QKV (W = concat [3072][1024]); z = blockIdx.y>>2:
//        z<2 -> transpose scatter to [bh][d][s]; z=2 -> v2 [bh][s][d].
// EPI 2: f32 out = acc + bias + res.   EPI 3: bf16 swiglu out.
// ---------------------------------------------------------------------------
template<int EPI>
__global__ __launch_bounds__(512, 4)
void g8k(const u16* __restrict__ Ag, const u16* __restrict__ Wg,
         const float* __restrict__ bq, const float* __restrict__ bk,
         const float* __restrict__ bv, const float* __restrict__ res,
         void* __restrict__ C0, void* __restrict__ C1, void* __restrict__ C2,
         int N, int K)
{
  __shared__ __align__(16) u16 lds[32768];   // A: [0,8192) B: [8192,24576); epi overlay 64KB
  const int tid = threadIdx.x;
  const int w = tid >> 6, l = tid & 63;
  const int fr = l & 15, fq = l >> 4;
  const int wm = w >> 2, wn = w & 3;         // 2M x 4N wave grid
  const int m0 = blockIdx.x << 7, n0 = blockIdx.y << 8;
  const int srow = w * 8 + (l >> 3);
  const int scol = ((l & 7) ^ (l >> 3)) << 3;   // inverse-swizzled source chunk
  const int NT = K >> 6;

  f32x4 acc[4][4] = {};
  const int rx = fr & 7;                     // read-side XOR key

  for (int t = 0; t < NT; ++t) {
    const int k0 = (t << 6) + scol;
    __syncthreads();                         // all waves done reading prev tile
    gll16(Ag + (size_t)(m0 + srow)        * K + k0, lds + w * 512);
    gll16(Ag + (size_t)(m0 + 64 + srow)   * K + k0, lds + (8 + w) * 512);
    gll16(Wg + (size_t)(n0 + srow)        * K + k0, lds + (16 + w) * 512);
    gll16(Wg + (size_t)(n0 + 64 + srow)   * K + k0, lds + (24 + w) * 512);
    gll16(Wg + (size_t)(n0 + 128 + srow)  * K + k0, lds + (32 + w) * 512);
    gll16(Wg + (size_t)(n0 + 192 + srow)  * K + k0, lds + (40 + w) * 512);
    __syncthreads();                         // vmcnt(0) drain + barrier
#pragma unroll
    for (int kk = 0; kk < 2; ++kk) {
      bf16x8 a[4], b[4];
#pragma unroll
      for (int mi = 0; mi < 4; ++mi)
        a[mi] = *(const bf16x8*)(lds + (wm * 64 + mi * 16 + fr) * 64
                                 + ((((kk << 2) + fq) ^ rx) << 3));
#pragma unroll
      for (int ni = 0; ni < 4; ++ni)
        b[ni] = *(const bf16x8*)(lds + 8192 + (wn * 64 + ni * 16 + fr) * 64
                                 + ((((kk << 2) + fq) ^ rx) << 3));
      __builtin_amdgcn_s_setprio(1);
#pragma unroll
      for (int mi = 0; mi < 4; ++mi)
#pragma unroll
        for (int ni = 0; ni < 4; ++ni)
          acc[mi][ni] = __builtin_amdgcn_mfma_f32_16x16x32_bf16(a[mi], b[ni],
                                                                acc[mi][ni], 0, 0, 0);
      __builtin_amdgcn_s_setprio(0);
    }
  }
  __syncthreads();                           // LDS free for epilogue overlay

  if constexpr (EPI == 2) {
    float* C = (float*)C0;
#pragma unroll
    for (int mi = 0; mi < 4; ++mi)
#pragma unroll
      for (int ni = 0; ni < 4; ++ni) {
        const int c = n0 + wn * 64 + ni * 16 + fr;
        const int r0 = m0 + wm * 64 + mi * 16 + fq * 4;
        const float bb = bq[c];
#pragma unroll
        for (int j = 0; j < 4; ++j)
          C[(size_t)(r0 + j) * N + c] = acc[mi][ni][j] + bb + res[(size_t)(r0 + j) * N + c];
      }
  } else if constexpr (EPI == 3) {
    u16* C = (u16*)C0;
#pragma unroll
    for (int mi = 0; mi < 4; ++mi)
#pragma unroll
      for (int ni = 0; ni < 4; ++ni) {
        const int c = n0 + wn * 64 + ni * 16 + fr;
        const int r0 = m0 + wm * 64 + mi * 16 + fq * 4;
        const float bb = bq[c];
#pragma unroll
        for (int j = 0; j < 4; ++j) {
          const float v = acc[mi][ni][j] + bb;
          const float sig = 1.0f / (1.0f + expf(-v));
          C[(size_t)(r0 + j) * N + c] = f2bf(v * sig + v);
        }
      }
  } else {
    // QKV epilogue: Cs[c(256)][r(128)] bf16 (64 KB overlay), swizzled
    const int z = blockIdx.y >> 2;
    const float* bias = z == 0 ? bq : (z == 1 ? bk : bv);
    const int n0l = n0 & 1023;
    const int bb = m0 >> 12, s0l = m0 & (S_LEN - 1);
#pragma unroll
    for (int mi = 0; mi < 4; ++mi)
#pragma unroll
      for (int ni = 0; ni < 4; ++ni) {
        const int c = wn * 64 + ni * 16 + fr;
        const int r0 = wm * 64 + mi * 16 + fq * 4;
        const float bv_ = bias[n0l + c];
        us4 pk;
#pragma unroll
        for (int j = 0; j < 4; ++j) pk[j] = f2bf(acc[mi][ni][j] + bv_);
        const int byte = ((c << 8) + (r0 << 1)) ^ ((c & 7) << 4);
        *(us4*)((char*)lds + byte) = pk;
      }
    __syncthreads();
    if (z < 2) {
      u16* Cout = z == 0 ? (u16*)C0 : (u16*)C1;
      const int c = tid & 255, half = tid >> 8;
      const int o = n0l + c, d = o >> 4, h = o & 15;
      const int xr = (c & 7) << 4;
      u16* dst = Cout + ((size_t)((bb << 10) + (h << 6) + d)) * S_LEN + s0l + half * 64;
#pragma unroll
      for (int u = 0; u < 8; ++u) {
        const int byte = ((c << 8) + (half << 7) + (u << 4)) ^ xr;
        const us8 v = *(const us8*)((char*)lds + byte);
        *(us8*)(dst + u * 8) = v;
      }
    } else {
      u16* Cv = (u16*)C2;
      const int d0 = n0l >> 4;
#pragma unroll
      for (int q = 0; q < 4; ++q) {
        const int idx = q * 512 + tid;       // 2048 = 16 h x 128 s
        const int h = idx >> 7, s = idx & 127;
        const int xr = (h & 7) << 4;
        us8 lo, hi;
#pragma unroll
        for (int dl = 0; dl < 8; ++dl) {
          lo[dl] = *(const u16*)((char*)lds + ((((h + dl * 16) << 8) + (s << 1)) ^ xr));
          hi[dl] = *(const u16*)((char*)lds + ((((h + (dl + 8) * 16) << 8) + (s << 1)) ^ xr));
        }
        u16* dst = Cv + ((size_t)(bb * 16 + h) * S_LEN + s0l + s) * 64 + d0;
        *(us8*)dst = lo;
        *(us8*)(dst + 8) = hi;
      }
    }
  }
}

// ---------------------------------------------------------------------------
// Fused scores + softmax per (b,h). One block per bh, 4 waves.
// ---------------------------------------------------------------------------
__global__ void __launch_bounds__(256)
att_sm_k(const u16* __restrict__ qt, const u16* __restrict__ kt,
         u16* __restrict__ P)
{
  __shared__ float red[4][64][64];   // [wave][e][d]
  const int bh = blockIdx.x;
  const int tid = threadIdx.x, w = tid >> 6, l = tid & 63;
  const int fr = l & 15, fq = l >> 4;
  const u16* Qb = qt + (size_t)bh * D_HEAD * S_LEN;
  const u16* Kb = kt + (size_t)bh * D_HEAD * S_LEN;
  f32x4 acc[4][4] = {};
  const int sb = w * 1024 + fq * 8;
  for (int ks = 0; ks < 32; ++ks) {
    const int s0 = sb + ks * 32;
    bf16x8 a[4], b[4];
#pragma unroll
    for (int m = 0; m < 4; ++m)
      a[m] = *(const bf16x8*)(Qb + (size_t)(m*16 + fr) * S_LEN + s0);
#pragma unroll
    for (int n = 0; n < 4; ++n)
      b[n] = *(const bf16x8*)(Kb + (size_t)(n*16 + fr) * S_LEN + s0);
#pragma unroll
    for (int m = 0; m < 4; ++m)
#pragma unroll
      for (int n = 0; n < 4; ++n)
        acc[m][n] = __builtin_amdgcn_mfma_f32_16x16x32_bf16(a[m], b[n], acc[m][n], 0, 0, 0);
  }
#pragma unroll
  for (int m = 0; m < 4; ++m)
#pragma unroll
    for (int n = 0; n < 4; ++n)
      *(f32x4*)&red[w][n*16 + fr][m*16 + fq*4] = acc[m][n];
  __syncthreads();

  const int d = tid >> 2, sub = tid & 3;
  float p[16];
  float mx = -1e30f;
#pragma unroll
  for (int i = 0; i < 16; ++i) {
    const int e = sub * 16 + i;
    float v = red[0][e][d] + red[1][e][d] + red[2][e][d] + red[3][e][d];
    v *= 0.125f;
    p[i] = v; mx = fmaxf(mx, v);
  }
  mx = fmaxf(mx, __shfl_xor(mx, 1, 64));
  mx = fmaxf(mx, __shfl_xor(mx, 2, 64));
  float sm = 0.0f;
#pragma unroll
  for (int i = 0; i < 16; ++i) { p[i] = expf(p[i] - mx); sm += p[i]; }
  sm += __shfl_xor(sm, 1, 64);
  sm += __shfl_xor(sm, 2, 64);
  const float inv = 1.0f / sm;
  us8 o0, o1;
#pragma unroll
  for (int i = 0; i < 8; ++i) { o0[i] = f2bf(p[i] * inv); o1[i] = f2bf(p[i+8] * inv); }
  u16* dst = P + (size_t)bh * 4096 + d * 64 + sub * 16;
  *(us8*)dst = o0;
  *(us8*)(dst + 8) = o1;
}

// ---------------------------------------------------------------------------
// PV via MFMA. out[d][s] = sum_e P[d][e] * V[e][s], V given as v2[s][e].
// ---------------------------------------------------------------------------
__global__ void __launch_bounds__(256)
pv2_k(const u16* __restrict__ P, const u16* __restrict__ v2,
      u16* __restrict__ ar)
{
  const int bh = blockIdx.x, sc = blockIdx.y;
  const int b = bh >> 4, h = bh & 15;
  const int tid = threadIdx.x, w = tid >> 6, l = tid & 63;
  const int fr = l & 15, fq = l >> 4;
  const u16* Pb = P + (size_t)bh * 4096;
  const u16* Vb = v2 + (size_t)bh * D_HEAD * S_LEN;

  bf16x8 a[4][2];
#pragma unroll
  for (int m = 0; m < 4; ++m)
#pragma unroll
    for (int ks = 0; ks < 2; ++ks)
      a[m][ks] = *(const bf16x8*)(Pb + (m*16 + fr) * 64 + ks*32 + fq*8);

  const int sw = sc * 512 + w * 128;
  f32x4 acc[8][4] = {};   // [n][m]
#pragma unroll
  for (int n = 0; n < 8; ++n) {
    const u16* vp = Vb + (size_t)(sw + n*16 + fr) * 64 + fq*8;
    const bf16x8 b0 = *(const bf16x8*)(vp);
    const bf16x8 b1 = *(const bf16x8*)(vp + 32);
#pragma unroll
    for (int m = 0; m < 4; ++m)
      acc[n][m] = __builtin_amdgcn_mfma_f32_16x16x32_bf16(a[m][0], b0, acc[n][m], 0, 0, 0);
#pragma unroll
    for (int m = 0; m < 4; ++m)
      acc[n][m] = __builtin_amdgcn_mfma_f32_16x16x32_bf16(a[m][1], b1, acc[n][m], 0, 0, 0);
  }

  const int shi = sc >> 1;
  const int col0 = (sc & 1) * 512 + w * 128;
#pragma unroll
  for (int m = 0; m < 4; ++m)
#pragma unroll
    for (int j = 0; j < 4; ++j) {
      const int d = m*16 + fq*4 + j;
      const size_t base = ((size_t)b * 4096 + (d << 6) + (h << 2) + shi) * 1024 + col0;
#pragma unroll
      for (int n = 0; n < 8; ++n)
        ar[base + n*16 + fr] = f2bf(acc[n][m][j]);
    }
}

// ---------------------------------------------------------------------------
extern "C" void kernel_launch(void* const* d_in, const int* in_sizes, int n_in,
                              void* d_out, int out_size, void* d_ws, size_t ws_size,
                              hipStream_t stream)
{
  const float* x     = (const float*)d_in[0];
  const float* scale = (const float*)d_in[1];
  const float* qw = (const float*)d_in[2];
  const float* qb = (const float*)d_in[3];
  const float* kw = (const float*)d_in[4];
  const float* kb = (const float*)d_in[5];
  const float* vw = (const float*)d_in[6];
  const float* vb = (const float*)d_in[7];
  const float* ow = (const float*)d_in[8];
  const float* ob = (const float*)d_in[9];
  const float* f1w = (const float*)d_in[10];
  const float* f1b = (const float*)d_in[11];
  const float* f2w = (const float*)d_in[12];
  const float* f2b = (const float*)d_in[13];
  float* out = (float*)d_out;

  const size_t TOKD = (size_t)TOKENS * D_MODEL;
  const size_t WSZ1 = (size_t)D_MODEL * D_MODEL;
  const size_t WSZ2 = (size_t)FF_DIM * D_MODEL;
  u16* xn = (u16*)d_ws;
  u16* qt = xn + TOKD;
  u16* kt = qt + TOKD;
  u16* v2 = kt + TOKD;
  u16* wq = v2 + TOKD;        // wq,wk,wv contiguous = concat [3072][1024]
  u16* wk = wq + WSZ1;
  u16* wv = wk + WSZ1;
  u16* wo = wv + WSZ1;
  u16* w1 = wo + WSZ1;
  u16* w2 = w1 + WSZ2;
  u16* Patt = w2 + WSZ2;
  u16* hbuf = kt;             // overlays kt+v2 (dead after attention)
  u16* ar = qt;               // overlays qt (dead after att_sm)

  dim3 blk(256);
  dim3 blk8(512);

  // 0. weights f32 -> bf16
  cvt6_k<<<8192, blk, 0, stream>>>(qw, kw, vw, ow, f1w, f2w, wq, wk, wv, wo, w1, w2);
  // 1. rmsnorm(x) -> xn
  rmsnorm_k<<<TOKENS, blk, 0, stream>>>(x, scale, xn);
  // 2. QKV (merged N=3072): qt/kt [bh][d][s], v2 [bh][s][d]
  g8k<0><<<dim3(TOKENS / 128, 12), blk8, 0, stream>>>(
      xn, wq, qb, kb, vb, nullptr, qt, kt, v2, 3072, D_MODEL);
  // 3. scores + softmax -> Patt
  att_sm_k<<<64, blk, 0, stream>>>(qt, kt, Patt);
  // 4. PV -> ar
  pv2_k<<<dim3(64, 8), blk, 0, stream>>>(Patt, v2, ar);
  // 5. O projection + bias + residual(x) -> out (f32)
  g8k<2><<<dim3(TOKENS / 128, D_MODEL / 256), blk8, 0, stream>>>(
      ar, wo, ob, nullptr, nullptr, x, out, nullptr, nullptr, D_MODEL, D_MODEL);
  // 6. rmsnorm(out) -> xn
  rmsnorm_k<<<TOKENS, blk, 0, stream>>>(out, scale, xn);
  // 7. FFN up + swiglu -> hbuf
  g8k<3><<<dim3(TOKENS / 128, FF_DIM / 256), blk8, 0, stream>>>(
      xn, w1, f1b, nullptr, nullptr, nullptr, hbuf, nullptr, nullptr, FF_DIM, D_MODEL);
  // 8. FFN down + bias + residual(out) -> out
  g8k<2><<<dim3(TOKENS / 128, D_MODEL / 256), blk8, 0, stream>>>(
      hbuf, w2, f2b, nullptr, nullptr, out, out, nullptr, nullptr, D_MODEL, FF_DIM);
}

// Round 11
// 441.427 us; speedup vs baseline: 1.1497x; 1.0295x over previous
//
#include <hip/hip_runtime.h>
#include <math.h>

typedef unsigned short u16;
typedef __attribute__((ext_vector_type(4))) unsigned short us4;
typedef __attribute__((ext_vector_type(8))) unsigned short us8;
typedef __attribute__((ext_vector_type(4))) float f4;
typedef __attribute__((ext_vector_type(8))) short bf16x8;
typedef __attribute__((ext_vector_type(4))) float f32x4;

#define S_LEN   4096
#define D_MODEL 1024
#define N_HEAD  16
#define D_HEAD  64
#define FF_DIM  2048
#define TOKENS  16384  // B*S

__device__ __forceinline__ float bf2f(u16 u) {
  union { float f; unsigned u; } x; x.u = ((unsigned)u) << 16; return x.f;
}
__device__ __forceinline__ u16 f2bf(float f) {
  union { float f; unsigned u; } x; x.f = f;
  return (u16)((x.u + 0x7FFFu + ((x.u >> 16) & 1u)) >> 16);
}

__device__ __forceinline__ void gll16(const void* g, void* l) {
  __builtin_amdgcn_global_load_lds(
      (const __attribute__((address_space(1))) void*)g,
      (__attribute__((address_space(3))) void*)l, 16, 0, 0);
}

// barrier + compiler-only memory fence (no extra runtime waits)
#define BARF() do { __builtin_amdgcn_s_barrier(); asm volatile("" ::: "memory"); } while (0)

// ---------------------------------------------------------------------------
// Fused f32 -> bf16 weight conversion. For wq/wk/wv (rms1) and w1 (rms2),
// fold scale[col] into the weight columns (rms scale commutes into W).
// ---------------------------------------------------------------------------
__global__ void __launch_bounds__(256)
cvt6_k(const float* __restrict__ qw, const float* __restrict__ kw,
       const float* __restrict__ vw, const float* __restrict__ ow,
       const float* __restrict__ f1w, const float* __restrict__ f2w,
       const float* __restrict__ scale,
       u16* __restrict__ wq, u16* __restrict__ wk, u16* __restrict__ wv,
       u16* __restrict__ wo, u16* __restrict__ w1, u16* __restrict__ w2)
{
  const int id = blockIdx.x;
  const float* src; u16* dst; int base; bool fold;
  if      (id < 1024) { src = qw;  dst = wq; base = 0;    fold = true;  }
  else if (id < 2048) { src = kw;  dst = wk; base = 1024; fold = true;  }
  else if (id < 3072) { src = vw;  dst = wv; base = 2048; fold = true;  }
  else if (id < 4096) { src = ow;  dst = wo; base = 3072; fold = false; }
  else if (id < 6144) { src = f1w; dst = w1; base = 4096; fold = true;  }
  else                { src = f2w; dst = w2; base = 6144; fold = false; }
  const size_t i = ((size_t)(id - base) * 256 + threadIdx.x) * 4;
  const f4 v = *(const f4*)(src + i);
  f4 sc = {1.f, 1.f, 1.f, 1.f};
  if (fold) sc = *(const f4*)(scale + (i & 1023));   // K=1024 rows for all folded
  us4 o;
  o[0] = f2bf(v[0] * sc[0]); o[1] = f2bf(v[1] * sc[1]);
  o[2] = f2bf(v[2] * sc[2]); o[3] = f2bf(v[3] * sc[3]);
  *(us4*)(dst + i) = o;
}

// ---------------------------------------------------------------------------
// x f32 -> xb bf16 (RAW, unnormalized) + per-row invr = rsqrt(mean(x^2)+eps).
// rms1 is folded: scale into weights (cvt6), invr into the QKV epilogue.
// ---------------------------------------------------------------------------
__global__ void __launch_bounds__(256)
cvtx_k(const float* __restrict__ in, u16* __restrict__ xb,
       float* __restrict__ invr)
{
  const int row = blockIdx.x;
  const int tid = threadIdx.x;
  const f4 v = *(const f4*)(in + (size_t)row * D_MODEL + tid * 4);
  float ss = v[0]*v[0] + v[1]*v[1] + v[2]*v[2] + v[3]*v[3];
#pragma unroll
  for (int off = 32; off > 0; off >>= 1) ss += __shfl_down(ss, off, 64);
  __shared__ float red[4];
  const int wid = tid >> 6, lane = tid & 63;
  if (lane == 0) red[wid] = ss;
  __syncthreads();
  if (tid == 0) {
    const float tot = red[0] + red[1] + red[2] + red[3];
    invr[row] = rsqrtf(tot * (1.0f / 1024.0f) + 1e-6f);
  }
  us4 o;
  o[0] = f2bf(v[0]); o[1] = f2bf(v[1]); o[2] = f2bf(v[2]); o[3] = f2bf(v[3]);
  *(us4*)(xb + (size_t)row * D_MODEL + tid * 4) = o;
}

// ---------------------------------------------------------------------------
// 256x256 GEMM, 8-phase gray-code schedule (r6 engine, best measured).
// EPI 0: QKV; out = acc*invr[row] + bias, scattered (z=blockIdx.y>>2):
//        z<2 -> [bh][d][s]; z=2 -> v2 [bh][s][d].  res param = invr1.
// EPI 2: f32 out = acc + bias + res (FFN-down).
// EPI 3: FFN-up: v = acc*rsqrt(sumsq[r]/1024+eps) + bias; swiglu; bf16 out.
//        res param = sumsq (f32, filled by EPI 4).
// EPI 4: O-proj: f32 out = acc+bias+res; also bf16 copy -> C1 and per-row
//        sum-of-squares atomics -> C2 (feeds EPI 3's rms).
// ---------------------------------------------------------------------------
template<int EPI>
__global__ __launch_bounds__(512, 2)
void g8k(const u16* __restrict__ Ag, const u16* __restrict__ Wg,
         const float* __restrict__ bq, const float* __restrict__ bk,
         const float* __restrict__ bv, const float* __restrict__ res,
         void* __restrict__ C0, void* __restrict__ C1, void* __restrict__ C2,
         int N, int K)
{
  __shared__ __align__(16) u16 lds[65536];   // A: [0,32768) B: [32768,65536)
  const int tid = threadIdx.x;
  const int w = tid >> 6, l = tid & 63;
  const int fr = l & 15, fq = l >> 4;
  const int wm = w >> 2, wn = w & 3;
  const int m0 = blockIdx.x << 8, n0 = blockIdx.y << 8;
  const int srow = w * 8 + (l >> 3);
  const int scol = ((l & 7) ^ (l >> 3)) << 3;  // inverse-swizzled source col (u16)
  const int NT = K >> 6;

  auto STAGE = [&](int isA, int hf, int bfs, int nt) {
    const u16* G = isA ? Ag : Wg;
    const int rb = (isA ? m0 : n0) + hf * 128 + srow;
    const int ks = (nt < NT ? nt << 6 : 0) + scol;
    u16* lb = lds + (isA ? 0 : 32768) + bfs * 16384 + hf * 8192 + w * 512;
    gll16(G + (size_t)rb * K + ks, lb);
    gll16(G + (size_t)(rb + 64) * K + ks, lb + 4096);
  };

  f32x4 acc[8][4] = {};
  bf16x8 afr[4][2], bfr[2][2];

  auto LDA = [&](int bf, int mh) {
#pragma unroll
    for (int i = 0; i < 4; ++i)
#pragma unroll
      for (int kk = 0; kk < 2; ++kk)
        afr[i][kk] = *(const bf16x8*)(lds + bf * 16384 + mh * 8192
                                      + (i * 32 + wm * 16 + fr) * 64
                                      + ((kk * 32 + fq * 8) ^ ((fr & 7) << 3)));
  };
  auto LDB = [&](int bf, int nh) {
#pragma unroll
    for (int jn = 0; jn < 2; ++jn)
#pragma unroll
      for (int kk = 0; kk < 2; ++kk)
        bfr[jn][kk] = *(const bf16x8*)(lds + 32768 + bf * 16384 + nh * 8192
                                       + (jn * 64 + wn * 16 + fr) * 64
                                       + ((kk * 32 + fq * 8) ^ ((fr & 7) << 3)));
  };
  auto MM = [&](int mhalf, int nhalf) {
    __builtin_amdgcn_s_setprio(1);
#pragma unroll
    for (int i = 0; i < 4; ++i)
#pragma unroll
      for (int jn = 0; jn < 2; ++jn)
#pragma unroll
        for (int kk = 0; kk < 2; ++kk)
          acc[mhalf * 4 + i][nhalf * 2 + jn] =
              __builtin_amdgcn_mfma_f32_16x16x32_bf16(afr[i][kk], bfr[jn][kk],
                                                      acc[mhalf * 4 + i][nhalf * 2 + jn], 0, 0, 0);
    __builtin_amdgcn_s_setprio(0);
  };

  // prologue: tile0 all 4 halves + A h0/h1 of tile1 (6 stages, 12 loads)
  STAGE(1, 0, 0, 0);
  STAGE(0, 0, 0, 0);
  STAGE(0, 1, 0, 0);
  STAGE(1, 1, 0, 0);
  STAGE(1, 0, 1, 1);
  STAGE(1, 1, 1, 1);
  asm volatile("s_waitcnt vmcnt(4)" ::: "memory");
  BARF();

  const int NIT = K >> 7;
  for (int it = 0; it < NIT; ++it) {
#pragma unroll
    for (int hf2 = 0; hf2 < 2; ++hf2) {
      const int n = 2 * it + hf2;
      const int bf = n & 1;
      // q0: (0,0)
      LDA(bf, 0); LDB(bf, 0);
      STAGE(0, 0, bf ^ 1, n + 1);
      BARF();
      MM(0, 0);
      BARF();
      // q1: (0,1)
      LDB(bf, 1);
      STAGE(0, 1, bf ^ 1, n + 1);
      BARF();
      MM(0, 1);
      BARF();
      // q2: (1,1)  (reuses bfr)
      LDA(bf, 1);
      STAGE(1, 0, bf, n + 2);
      BARF();
      MM(1, 1);
      BARF();
      // q3: (1,0)
      LDB(bf, 0);
      STAGE(1, 1, bf, n + 2);
      BARF();
      MM(1, 0);
      asm volatile("s_waitcnt vmcnt(4)" ::: "memory");
      BARF();
    }
  }
  asm volatile("s_waitcnt vmcnt(0)" ::: "memory");
  __builtin_amdgcn_s_barrier();
  asm volatile("" ::: "memory");

  if constexpr (EPI == 2) {
    float* C = (float*)C0;
#pragma unroll
    for (int mi = 0; mi < 8; ++mi)
#pragma unroll
      for (int ni = 0; ni < 4; ++ni) {
        const int c = n0 + ni * 64 + wn * 16 + fr;
        const int r0 = m0 + mi * 32 + wm * 16 + fq * 4;
        const float bb = bq[c];
#pragma unroll
        for (int j = 0; j < 4; ++j)
          C[(size_t)(r0 + j) * N + c] = acc[mi][ni][j] + bb + res[(size_t)(r0 + j) * N + c];
      }
  } else if constexpr (EPI == 4) {
    float* C = (float*)C0;
    u16* OB = (u16*)C1;
    float* SQ = (float*)C2;
#pragma unroll
    for (int mi = 0; mi < 8; ++mi) {
      const int r0 = m0 + mi * 32 + wm * 16 + fq * 4;
      float part0 = 0.f, part1 = 0.f, part2 = 0.f, part3 = 0.f;
#pragma unroll
      for (int ni = 0; ni < 4; ++ni) {
        const int c = n0 + ni * 64 + wn * 16 + fr;
        const float bb = bq[c];
#pragma unroll
        for (int j = 0; j < 4; ++j) {
          const float v = acc[mi][ni][j] + bb + res[(size_t)(r0 + j) * N + c];
          C[(size_t)(r0 + j) * N + c] = v;
          OB[(size_t)(r0 + j) * N + c] = f2bf(v);
          if (j == 0) part0 += v * v;
          else if (j == 1) part1 += v * v;
          else if (j == 2) part2 += v * v;
          else part3 += v * v;
        }
      }
      float part[4] = {part0, part1, part2, part3};
#pragma unroll
      for (int j = 0; j < 4; ++j) {
        float p = part[j];
        p += __shfl_xor(p, 1, 64);
        p += __shfl_xor(p, 2, 64);
        p += __shfl_xor(p, 4, 64);
        p += __shfl_xor(p, 8, 64);
        if (fr == 0) atomicAdd(&SQ[r0 + j], p);
      }
    }
  } else if constexpr (EPI == 3) {
    u16* C = (u16*)C0;
    const float* SQ = res;
#pragma unroll
    for (int mi = 0; mi < 8; ++mi) {
      const int r0 = m0 + mi * 32 + wm * 16 + fq * 4;
      const f4 sq4 = *(const f4*)(SQ + r0);
      float iv[4];
#pragma unroll
      for (int j = 0; j < 4; ++j) iv[j] = rsqrtf(sq4[j] * (1.0f / 1024.0f) + 1e-6f);
#pragma unroll
      for (int ni = 0; ni < 4; ++ni) {
        const int c = n0 + ni * 64 + wn * 16 + fr;
        const float bb = bq[c];
#pragma unroll
        for (int j = 0; j < 4; ++j) {
          const float v = acc[mi][ni][j] * iv[j] + bb;
          const float sig = 1.0f / (1.0f + expf(-v));
          C[(size_t)(r0 + j) * N + c] = f2bf(v * sig + v);
        }
      }
    }
  } else {
    // QKV epilogue: out = acc*invr[row] + bias, packed transposed into LDS
    const int z = blockIdx.y >> 2;
    const float* bias = z == 0 ? bq : (z == 1 ? bk : bv);
    const float* IV = res;           // invr1
    const int n0l = n0 & 1023;
    const int bb = m0 >> 12, s0l = m0 & (S_LEN - 1);
#pragma unroll
    for (int mi = 0; mi < 8; ++mi)
#pragma unroll
      for (int ni = 0; ni < 4; ++ni) {
        const int c = ni * 64 + wn * 16 + fr;
        const int r0 = mi * 32 + wm * 16 + fq * 4;
        const f4 iv4 = *(const f4*)(IV + m0 + r0);
        const float bv_ = bias[n0l + c];
        us4 pk;
#pragma unroll
        for (int j = 0; j < 4; ++j) pk[j] = f2bf(acc[mi][ni][j] * iv4[j] + bv_);
        const int byte = ((c << 9) + (r0 << 1)) ^ ((c & 7) << 4);
        *(us4*)((char*)lds + byte) = pk;
      }
    __syncthreads();
    if (z < 2) {
      u16* Cout = z == 0 ? (u16*)C0 : (u16*)C1;
      const int c = tid & 255, half = tid >> 8;
      const int o = n0l + c, d = o >> 4, h = o & 15;
      const int xr = (c & 7) << 4;
      u16* dst = Cout + ((size_t)((bb << 10) + (h << 6) + d)) * S_LEN + s0l + half * 128;
#pragma unroll
      for (int u = 0; u < 16; ++u) {
        const int byte = ((c << 9) + (half << 8) + (u << 4)) ^ xr;
        const us8 v = *(const us8*)((char*)lds + byte);
        *(us8*)(dst + u * 8) = v;
      }
    } else {
      u16* Cv = (u16*)C2;
      const int d0 = n0l >> 4;
#pragma unroll
      for (int q2 = 0; q2 < 8; ++q2) {
        const int idx = q2 * 512 + tid;
        const int h = idx >> 8, r = idx & 255;
        const int xr = (h & 7) << 4;
        us8 lo, hi;
#pragma unroll
        for (int dl = 0; dl < 8; ++dl) {
          lo[dl] = *(const u16*)((char*)lds + ((((h + dl * 16) << 9) + (r << 1)) ^ xr));
          hi[dl] = *(const u16*)((char*)lds + ((((h + (dl + 8) * 16) << 9) + (r << 1)) ^ xr));
        }
        u16* dst = Cv + ((size_t)(bb * 16 + h) * S_LEN + s0l + r) * 64 + d0;
        *(us8*)dst = lo;
        *(us8*)(dst + 8) = hi;
      }
    }
  }
}

// ---------------------------------------------------------------------------
// Fused scores + softmax per (b,h). One block per bh, 4 waves.
// ---------------------------------------------------------------------------
__global__ void __launch_bounds__(256)
att_sm_k(const u16* __restrict__ qt, const u16* __restrict__ kt,
         u16* __restrict__ P)
{
  __shared__ float red[4][64][64];   // [wave][e][d]
  const int bh = blockIdx.x;
  const int tid = threadIdx.x, w = tid >> 6, l = tid & 63;
  const int fr = l & 15, fq = l >> 4;
  const u16* Qb = qt + (size_t)bh * D_HEAD * S_LEN;
  const u16* Kb = kt + (size_t)bh * D_HEAD * S_LEN;
  f32x4 acc[4][4] = {};
  const int sb = w * 1024 + fq * 8;
  for (int ks = 0; ks < 32; ++ks) {
    const int s0 = sb + ks * 32;
    bf16x8 a[4], b[4];
#pragma unroll
    for (int m = 0; m < 4; ++m)
      a[m] = *(const bf16x8*)(Qb + (size_t)(m*16 + fr) * S_LEN + s0);
#pragma unroll
    for (int n = 0; n < 4; ++n)
      b[n] = *(const bf16x8*)(Kb + (size_t)(n*16 + fr) * S_LEN + s0);
#pragma unroll
    for (int m = 0; m < 4; ++m)
#pragma unroll
      for (int n = 0; n < 4; ++n)
        acc[m][n] = __builtin_amdgcn_mfma_f32_16x16x32_bf16(a[m], b[n], acc[m][n], 0, 0, 0);
  }
#pragma unroll
  for (int m = 0; m < 4; ++m)
#pragma unroll
    for (int n = 0; n < 4; ++n)
      *(f32x4*)&red[w][n*16 + fr][m*16 + fq*4] = acc[m][n];
  __syncthreads();

  const int d = tid >> 2, sub = tid & 3;
  float p[16];
  float mx = -1e30f;
#pragma unroll
  for (int i = 0; i < 16; ++i) {
    const int e = sub * 16 + i;
    float v = red[0][e][d] + red[1][e][d] + red[2][e][d] + red[3][e][d];
    v *= 0.125f;
    p[i] = v; mx = fmaxf(mx, v);
  }
  mx = fmaxf(mx, __shfl_xor(mx, 1, 64));
  mx = fmaxf(mx, __shfl_xor(mx, 2, 64));
  float sm = 0.0f;
#pragma unroll
  for (int i = 0; i < 16; ++i) { p[i] = expf(p[i] - mx); sm += p[i]; }
  sm += __shfl_xor(sm, 1, 64);
  sm += __shfl_xor(sm, 2, 64);
  const float inv = 1.0f / sm;
  us8 o0, o1;
#pragma unroll
  for (int i = 0; i < 8; ++i) { o0[i] = f2bf(p[i] * inv); o1[i] = f2bf(p[i+8] * inv); }
  u16* dst = P + (size_t)bh * 4096 + d * 64 + sub * 16;
  *(us8*)dst = o0;
  *(us8*)(dst + 8) = o1;
}

// ---------------------------------------------------------------------------
// PV via MFMA. out[d][s] = sum_e P[d][e] * V[e][s], V given as v2[s][e].
// ---------------------------------------------------------------------------
__global__ void __launch_bounds__(256)
pv2_k(const u16* __restrict__ P, const u16* __restrict__ v2,
      u16* __restrict__ ar)
{
  const int bh = blockIdx.x, sc = blockIdx.y;
  const int b = bh >> 4, h = bh & 15;
  const int tid = threadIdx.x, w = tid >> 6, l = tid & 63;
  const int fr = l & 15, fq = l >> 4;
  const u16* Pb = P + (size_t)bh * 4096;
  const u16* Vb = v2 + (size_t)bh * D_HEAD * S_LEN;

  bf16x8 a[4][2];
#pragma unroll
  for (int m = 0; m < 4; ++m)
#pragma unroll
    for (int ks = 0; ks < 2; ++ks)
      a[m][ks] = *(const bf16x8*)(Pb + (m*16 + fr) * 64 + ks*32 + fq*8);

  const int sw = sc * 512 + w * 128;
  f32x4 acc[8][4] = {};   // [n][m]
#pragma unroll
  for (int n = 0; n < 8; ++n) {
    const u16* vp = Vb + (size_t)(sw + n*16 + fr) * 64 + fq*8;
    const bf16x8 b0 = *(const bf16x8*)(vp);
    const bf16x8 b1 = *(const bf16x8*)(vp + 32);
#pragma unroll
    for (int m = 0; m < 4; ++m)
      acc[n][m] = __builtin_amdgcn_mfma_f32_16x16x32_bf16(a[m][0], b0, acc[n][m], 0, 0, 0);
#pragma unroll
    for (int m = 0; m < 4; ++m)
      acc[n][m] = __builtin_amdgcn_mfma_f32_16x16x32_bf16(a[m][1], b1, acc[n][m], 0, 0, 0);
  }

  const int shi = sc >> 1;
  const int col0 = (sc & 1) * 512 + w * 128;
#pragma unroll
  for (int m = 0; m < 4; ++m)
#pragma unroll
    for (int j = 0; j < 4; ++j) {
      const int d = m*16 + fq*4 + j;
      const size_t base = ((size_t)b * 4096 + (d << 6) + (h << 2) + shi) * 1024 + col0;
#pragma unroll
      for (int n = 0; n < 8; ++n)
        ar[base + n*16 + fr] = f2bf(acc[n][m][j]);
    }
}

// ---------------------------------------------------------------------------
extern "C" void kernel_launch(void* const* d_in, const int* in_sizes, int n_in,
                              void* d_out, int out_size, void* d_ws, size_t ws_size,
                              hipStream_t stream)
{
  const float* x     = (const float*)d_in[0];
  const float* scale = (const float*)d_in[1];
  const float* qw = (const float*)d_in[2];
  const float* qb = (const float*)d_in[3];
  const float* kw = (const float*)d_in[4];
  const float* kb = (const float*)d_in[5];
  const float* vw = (const float*)d_in[6];
  const float* vb = (const float*)d_in[7];
  const float* ow = (const float*)d_in[8];
  const float* ob = (const float*)d_in[9];
  const float* f1w = (const float*)d_in[10];
  const float* f1b = (const float*)d_in[11];
  const float* f2w = (const float*)d_in[12];
  const float* f2b = (const float*)d_in[13];
  float* out = (float*)d_out;

  const size_t TOKD = (size_t)TOKENS * D_MODEL;
  const size_t WSZ1 = (size_t)D_MODEL * D_MODEL;
  const size_t WSZ2 = (size_t)FF_DIM * D_MODEL;
  u16* xb = (u16*)d_ws;       // raw x bf16; later reused as outb (bf16 copy of out)
  u16* qt = xb + TOKD;
  u16* kt = qt + TOKD;
  u16* v2 = kt + TOKD;
  u16* wq = v2 + TOKD;        // wq,wk,wv contiguous = concat [3072][1024]
  u16* wk = wq + WSZ1;
  u16* wv = wk + WSZ1;
  u16* wo = wv + WSZ1;
  u16* w1 = wo + WSZ1;
  u16* w2 = w1 + WSZ2;
  u16* Patt = w2 + WSZ2;
  float* invr1 = (float*)(Patt + (size_t)64 * 64 * 64);
  float* sumsq = invr1 + TOKENS;
  u16* hbuf = kt;             // overlays kt+v2 (dead after attention)
  u16* ar = qt;               // overlays qt (dead after att_sm)
  u16* outb = xb;             // overlays xb (dead after QKV)

  dim3 blk(256);
  dim3 blk8(512);

  // sumsq for fused rms2 must start at zero every call
  hipMemsetAsync(sumsq, 0, TOKENS * sizeof(float), stream);
  // 0. weights f32 -> bf16, scale folded into wq/wk/wv/w1 columns
  cvt6_k<<<8192, blk, 0, stream>>>(qw, kw, vw, ow, f1w, f2w, scale,
                                   wq, wk, wv, wo, w1, w2);
  // 1. x -> xb (raw bf16) + invr1 (fused rms1)
  cvtx_k<<<TOKENS, blk, 0, stream>>>(x, xb, invr1);
  // 2. QKV (merged N=3072): qt/kt [bh][d][s], v2 [bh][s][d]; *invr1 in epilogue
  g8k<0><<<dim3(TOKENS / 256, 12), blk8, 0, stream>>>(
      xb, wq, qb, kb, vb, invr1, qt, kt, v2, 3072, D_MODEL);
  // 3. scores + softmax -> Patt
  att_sm_k<<<64, blk, 0, stream>>>(qt, kt, Patt);
  // 4. PV -> ar
  pv2_k<<<dim3(64, 8), blk, 0, stream>>>(Patt, v2, ar);
  // 5. O projection + bias + residual(x) -> out f32, outb bf16, sumsq atomics
  g8k<4><<<dim3(TOKENS / 256, D_MODEL / 256), blk8, 0, stream>>>(
      ar, wo, ob, nullptr, nullptr, x, out, outb, sumsq, D_MODEL, D_MODEL);
  // 6. FFN up (A = outb, rms2 fused via sumsq) + swiglu -> hbuf
  g8k<3><<<dim3(TOKENS / 256, FF_DIM / 256), blk8, 0, stream>>>(
      outb, w1, f1b, nullptr, nullptr, sumsq, hbuf, nullptr, nullptr, FF_DIM, D_MODEL);
  // 7. FFN down + bias + residual(out) -> out
  g8k<2><<<dim3(TOKENS / 256, D_MODEL / 256), blk8, 0, stream>>>(
      hbuf, w2, f2b, nullptr, nullptr, out, out, nullptr, nullptr, D_MODEL, FF_DIM);
}